// Round 10
// baseline (265.647 us; speedup 1.0000x reference)
//
#include <hip/hip_runtime.h>
#include <stdint.h>

// SelfAttentionLayer: x [32,32,32,512] fp32 -> out fp32 same shape
#define B_ 32
#define N_ 1024   // tokens per batch (H*W)
#define C_ 512
#define D_ 64     // DQK

typedef __attribute__((ext_vector_type(8))) __bf16 bf8;   // MFMA A/B frag (4 VGPRs)
typedef __attribute__((ext_vector_type(4))) float f32x4;  // MFMA C/D frag

typedef const __attribute__((address_space(1))) void* gp_t;
typedef __attribute__((address_space(3))) void* lp_t;

__device__ inline void g2l16(const void* g, void* l) {
    // async global->LDS, 16B/lane; LDS dest = uniform base + lane*16
    __builtin_amdgcn_global_load_lds((gp_t)g, (lp_t)l, 16, 0, 0);
}

__device__ inline float b2f(unsigned short u) {
    return __uint_as_float(((unsigned)u) << 16);
}
__device__ inline unsigned short f2b(float f) {   // f32 -> bf16 bits, RNE
    unsigned u = __float_as_uint(f);
    u += 0x7FFF + ((u >> 16) & 1);
    return (unsigned short)(u >> 16);
}

#define MFMA16(a, b, c) __builtin_amdgcn_mfma_f32_16x16x32_bf16((a), (b), (c), 0, 0, 0)

// fragment loads from a staged (frag-order) 128x64 tile pair
__device__ __forceinline__ void ld_frags(const unsigned short* As, const unsigned short* Bs,
                                         int wm, int wn, int lane,
                                         bf8 (&a)[2][4], bf8 (&bb)[2][4]) {
    #pragma unroll
    for (int kq = 0; kq < 2; ++kq) {
        #pragma unroll
        for (int ti = 0; ti < 4; ++ti)
            a[kq][ti] = *(const bf8*)&As[((wm * 4 + ti) * 2 + kq) * 512 + lane * 8];
        #pragma unroll
        for (int tj = 0; tj < 4; ++tj)
            bb[kq][tj] = *(const bf8*)&Bs[((wn * 4 + tj) * 2 + kq) * 512 + lane * 8];
    }
}

__device__ __forceinline__ void do_mfma(const bf8 (&a)[2][4], const bf8 (&bb)[2][4],
                                        f32x4 (&acc)[4][4]) {
    #pragma unroll
    for (int kq = 0; kq < 2; ++kq)
        #pragma unroll
        for (int ti = 0; ti < 4; ++ti)
            #pragma unroll
            for (int tj = 0; tj < 4; ++tj)
                acc[ti][tj] = MFMA16(a[kq][ti], bb[kq][tj], acc[ti][tj]);
}

// ---------------------------------------------------------------------------
// Kernel 0 (fused): x fp32 -> bf16  AND  weight transpose+cvt -> WT[640][512].
// blocks [0,16384): xcvt quad-wise; blocks [16384,17664): wtrans.
// ---------------------------------------------------------------------------
__global__ __launch_bounds__(256) void prep(
    const float* __restrict__ x, unsigned short* __restrict__ xb,
    const float* __restrict__ wq, const float* __restrict__ wk,
    const float* __restrict__ wv, unsigned short* __restrict__ wt)
{
    int bid = blockIdx.x;
    if (bid < 16384) {
        int i = bid * 256 + threadIdx.x;         // quad index, exact grid
        float4 f = ((const float4*)x)[i];
        ushort4 o;
        o.x = f2b(f.x); o.y = f2b(f.y); o.z = f2b(f.z); o.w = f2b(f.w);
        ((ushort4*)xb)[i] = o;
    } else {
        int t = (bid - 16384) * 256 + threadIdx.x;   // 0..327679
        int co = t >> 9;          // /512
        int ci = t & 511;
        const float* src;
        int col, cout;
        if (co < 64)       { src = wq; col = co;       cout = 64;  }
        else if (co < 128) { src = wk; col = co - 64;  cout = 64;  }
        else               { src = wv; col = co - 128; cout = 512; }
        wt[t] = f2b(src[(size_t)ci * cout + col]);
    }
}

// ---------------------------------------------------------------------------
// Kernel 1: QKV projection GEMM. [32768,512]bf16 @ WT[640,512]^T.
// 2-deep counted-vmcnt pipeline, XCD-grouped flat grid (unchanged, r7).
// ---------------------------------------------------------------------------
__global__ __launch_bounds__(256) void qkv(
    const unsigned short* __restrict__ xb,
    const unsigned short* __restrict__ WT,
    const float* __restrict__ bq, const float* __restrict__ bk,
    const float* __restrict__ bv,
    unsigned short* __restrict__ q, unsigned short* __restrict__ k,
    unsigned short* __restrict__ vT)
{
    // XCD-grouped decode: f&7 = XCD (dispatch round-robin).
    const int f_  = blockIdx.x;
    const int xcd = f_ & 7;
    const int s_  = f_ >> 3;          // 0..159 slot within XCD
    const int rb  = xcd * 32 + s_ / 5;    // row-tile 0..255 (contig per XCD)
    const int cb  = s_ % 5;               // 5 col-blocks share one rb panel

    const int tid = threadIdx.x;
    const int lane = tid & 63;
    const int wave = tid >> 6;
    const int wm = wave >> 1, wn = wave & 1;
    const int lr = lane & 15;     // frag row/col within 16
    const int lk = lane >> 4;     // k-octet 0..3

    __shared__ unsigned short SM[32768];      // 64 KB: As[2][8192] | Bs[2][8192]
    unsigned short* TB = SM;                  // aliased transpose buf 128x132 (16896)

    const int row0 = rb * 128;
    const int col0 = cb * 128;                // within [640]

    f32x4 zero4 = {0.f, 0.f, 0.f, 0.f};
    f32x4 acc[4][4];
    #pragma unroll
    for (int i = 0; i < 4; ++i)
        #pragma unroll
        for (int j = 0; j < 4; ++j) acc[i][j] = zero4;

    auto stage = [&](int buf, int kk) {       // 8 loads/wave
        unsigned short* As = SM + buf * 8192;
        unsigned short* Bs = SM + 16384 + buf * 8192;
        #pragma unroll
        for (int i = 0; i < 4; ++i) {          // 16 frags each for A and B
            int f = wave * 4 + i;
            int t = f >> 1, kq = f & 1;
            g2l16(xb + (size_t)(row0 + t * 16 + lr) * C_ + kk + kq * 32 + lk * 8,
                  &As[f * 512]);
            g2l16(WT + (size_t)(col0 + t * 16 + lr) * C_ + kk + kq * 32 + lk * 8,
                  &Bs[f * 512]);
        }
    };

    stage(0, 0);
    stage(1, 64);
    int cur = 0;
    for (int t = 0; t < 6; ++t) {             // steady state: tiles 0..5
        asm volatile("s_waitcnt vmcnt(8)" ::: "memory");   // tile t landed
        __builtin_amdgcn_s_barrier();
        bf8 a[2][4], bb[2][4];
        ld_frags(SM + cur * 8192, SM + 16384 + cur * 8192, wm, wn, lane, a, bb);
        asm volatile("s_waitcnt lgkmcnt(0)" ::: "memory"); // my reads done
        __builtin_amdgcn_s_barrier();                       // everyone's reads done
        stage(cur, (t + 2) * 64);             // reuse buffer for tile t+2
        do_mfma(a, bb, acc);
        cur ^= 1;
    }
    {   // tile 6: wait oldest 8, tile 7 still in flight
        asm volatile("s_waitcnt vmcnt(8)" ::: "memory");
        __builtin_amdgcn_s_barrier();
        bf8 a[2][4], bb[2][4];
        ld_frags(SM + cur * 8192, SM + 16384 + cur * 8192, wm, wn, lane, a, bb);
        do_mfma(a, bb, acc);
        cur ^= 1;
    }
    {   // tile 7: final drain
        asm volatile("s_waitcnt vmcnt(0)" ::: "memory");
        __builtin_amdgcn_s_barrier();
        bf8 a[2][4], bb[2][4];
        ld_frags(SM + cur * 8192, SM + 16384 + cur * 8192, wm, wn, lane, a, bb);
        do_mfma(a, bb, acc);
    }

    if (cb == 0) {
        // wn==0 waves own cols 0..63 (-> q), wn==1 own cols 64..127 (-> k)
        unsigned short* outp = (wn == 0) ? q : k;
        const float* bias = (wn == 0) ? bq : bk;
        #pragma unroll
        for (int ti = 0; ti < 4; ++ti)
            #pragma unroll
            for (int tj = 0; tj < 4; ++tj) {
                int col = tj * 16 + lr;           // 0..63 within q or k
                float bi = bias[col];
                #pragma unroll
                for (int r = 0; r < 4; ++r) {
                    int row = row0 + wm * 64 + ti * 16 + lk * 4 + r;
                    outp[(size_t)row * D_ + col] = f2b(acc[ti][tj][r] + bi);
                }
            }
    } else {
        const int colv = (cb - 1) * 128;          // v col base (0..511)
        __syncthreads();                          // all frag reads done; TB aliases SM
        #pragma unroll
        for (int ti = 0; ti < 4; ++ti)
            #pragma unroll
            for (int tj = 0; tj < 4; ++tj) {
                int c = wn * 64 + tj * 16 + lr;   // 0..127 within block
                float bi = bv[colv + c];
                int tok = wm * 64 + ti * 16 + lk * 4;
                ushort4 o;
                o.x = f2b(acc[ti][tj][0] + bi);
                o.y = f2b(acc[ti][tj][1] + bi);
                o.z = f2b(acc[ti][tj][2] + bi);
                o.w = f2b(acc[ti][tj][3] + bi);
                *(ushort4*)&TB[c * 132 + tok] = o;
            }
        __syncthreads();
        const int b  = row0 >> 10;
        const int n0 = row0 & 1023;
        #pragma unroll
        for (int i = 0; i < 16; ++i) {
            int idx = tid + 256 * i;              // 0..4095
            int c = idx >> 5, ch = idx & 31;
            ushort4 t4 = *(const ushort4*)&TB[c * 132 + ch * 4];
            *(ushort4*)&vT[((size_t)(b * C_ + colv + c)) * N_ + n0 + ch * 4] = t4;
        }
    }
}

// ---------------------------------------------------------------------------
// Kernel 2: scores + softmax -> P bf16 [b][n][m].  (unchanged, r7)
// ---------------------------------------------------------------------------
#define SLD 1032   // S leading dim (shorts), pad 8 to break 2048B bank period
__global__ __launch_bounds__(256) void scores(
    const unsigned short* __restrict__ q,
    const unsigned short* __restrict__ k,
    unsigned short* __restrict__ P)
{
    const int f_  = blockIdx.x;
    const int xcd = f_ & 7;
    const int s_  = f_ >> 3;              // 0..255 slot within XCD
    const int b   = xcd * 4 + (s_ >> 6);  // batch (same-b => same xcd)
    const int qt  = s_ & 63;              // q-tile within batch

    const int tid = threadIdx.x, lane = tid & 63, wave = tid >> 6;
    const int lr = lane & 15, lk = lane >> 4;
    __shared__ unsigned short S[16 * SLD];      // bf16 scores, 33 KB

    const int n0 = qt * 16;
    const unsigned short* qrow = q + (size_t)(b * N_ + n0 + lr) * D_ + lk * 8;
    bf8 qa0 = *(const bf8*)(qrow);
    bf8 qa1 = *(const bf8*)(qrow + 32);

    const int m0w = wave * 256;
    #pragma unroll 4
    for (int mt = 0; mt < 16; ++mt) {
        int m = m0w + mt * 16;
        const unsigned short* krow = k + (size_t)(b * N_ + m + lr) * D_ + lk * 8;
        bf8 kb0 = *(const bf8*)(krow);
        bf8 kb1 = *(const bf8*)(krow + 32);
        f32x4 s = {0.f, 0.f, 0.f, 0.f};
        s = MFMA16(qa0, kb0, s);
        s = MFMA16(qa1, kb1, s);
        #pragma unroll
        for (int r = 0; r < 4; ++r)
            S[(lk * 4 + r) * SLD + m + lr] = f2b(s[r] * 0.125f);  // 1/sqrt(64)
    }
    __syncthreads();

    #pragma unroll
    for (int rr4 = 0; rr4 < 4; ++rr4) {
        int rr = wave * 4 + rr4;
        float vals[16];
        float mx = -1e30f;
        #pragma unroll
        for (int j = 0; j < 16; ++j) {
            vals[j] = b2f(S[rr * SLD + j * 64 + lane]);
            mx = fmaxf(mx, vals[j]);
        }
        #pragma unroll
        for (int off = 32; off; off >>= 1) mx = fmaxf(mx, __shfl_xor(mx, off));
        float sum = 0.f;
        #pragma unroll
        for (int j = 0; j < 16; ++j) { vals[j] = __expf(vals[j] - mx); sum += vals[j]; }
        #pragma unroll
        for (int off = 32; off; off >>= 1) sum += __shfl_xor(sum, off);
        float inv = 1.f / sum;
        unsigned short* pp = P + (size_t)(b * N_ + n0 + rr) * N_;
        #pragma unroll
        for (int j = 0; j < 16; ++j) pp[j * 64 + lane] = f2b(vals[j] * inv);
    }
}

// ---------------------------------------------------------------------------
// Kernel 3: O = P @ V + x (residual), fp32 out.  NEW geometry: 256x128 tile,
// 512 blocks -> 2 blocks/CU (LDS 72 KB: 3-buffer ring, BK=32).  The second
// resident block overlaps its GEMM (LDS+MFMA) with the other's fp32 epilogue
// burst (HBM), which round-9 counters showed fully exposed at 1 block/CU.
// 8 waves: 4M x 2N, each wave 64x64 out, acc[4][4] (64 VGPR).
// One barrier per K-step; counted vmcnt(3) (3 loads/thread/tile, 2 tiles in
// flight); setprio around MFMA cluster; sched_barrier after lgkm (rule #18).
// XCD-bound per batch (16 tiles/batch on one XCD).
// ---------------------------------------------------------------------------
__global__ __launch_bounds__(512, 4) void pv(
    const unsigned short* __restrict__ P,
    const unsigned short* __restrict__ vT,
    const float* __restrict__ x,
    float* __restrict__ out)
{
    // 512 blocks: xcd = f&7; 4 batches/XCD x 16 tiles (4M x 4N).
    const int f_   = blockIdx.x;
    const int xcd  = f_ & 7;
    const int s_   = f_ >> 3;             // 0..63 slot within XCD
    const int b    = xcd * 4 + (s_ >> 4); // batch (same-b => same xcd)
    const int w_   = s_ & 15;             // tile within batch
    const int m0   = (w_ & 3) * 256;
    const int c0   = (w_ >> 2) * 128;

    const int tid = threadIdx.x, lane = tid & 63, wave = tid >> 6;  // 8 waves
    const int wm = wave >> 1;             // 0..3 -> rows wm*64
    const int wn = wave & 1;              // 0..1 -> cols wn*64
    const int lr = lane & 15, lk = lane >> 4;

    __shared__ unsigned short SM[36864];  // 72 KB = 3 bufs x (A 8192 | B 4096 shorts)

    f32x4 zero4 = {0.f, 0.f, 0.f, 0.f};
    f32x4 acc[4][4];
    #pragma unroll
    for (int i = 0; i < 4; ++i)
        #pragma unroll
        for (int j = 0; j < 4; ++j) acc[i][j] = zero4;

    const unsigned short* Pb = P  + (size_t)b * N_ * N_;
    const unsigned short* Vb = vT + (size_t)b * C_ * N_;

    auto stage = [&](int t32, int buf) {  // 3 loads/thread; 24 frags (A16 + B8)
        unsigned short* Ab = SM + buf * 12288;
        unsigned short* Bb = Ab + 8192;
        const int kk = t32 * 32;
        #pragma unroll
        for (int i = 0; i < 3; ++i) {
            int f = wave * 3 + i;         // 0..23, wave-uniform per instance
            if (f < 16) {
                g2l16(Pb + (size_t)(m0 + f * 16 + lr) * N_ + kk + lk * 8,
                      &Ab[f * 512]);
            } else {
                int g = f - 16;
                g2l16(Vb + (size_t)(c0 + g * 16 + lr) * N_ + kk + lk * 8,
                      &Bb[g * 512]);
            }
        }
    };

    auto compute = [&](int buf) {
        const unsigned short* Ab = SM + buf * 12288;
        const unsigned short* Bb = Ab + 8192;
        bf8 a[4], bb[4];
        #pragma unroll
        for (int ti = 0; ti < 4; ++ti)
            a[ti] = *(const bf8*)&Ab[(wm * 4 + ti) * 512 + lane * 8];
        #pragma unroll
        for (int tj = 0; tj < 4; ++tj)
            bb[tj] = *(const bf8*)&Bb[(wn * 4 + tj) * 512 + lane * 8];
        asm volatile("s_waitcnt lgkmcnt(0)" ::: "memory");
        __builtin_amdgcn_sched_barrier(0);           // rule #18: pin MFMAs below
        __builtin_amdgcn_s_setprio(1);
        #pragma unroll
        for (int ti = 0; ti < 4; ++ti)
            #pragma unroll
            for (int tj = 0; tj < 4; ++tj)
                acc[ti][tj] = MFMA16(a[ti], bb[tj], acc[ti][tj]);
        __builtin_amdgcn_s_setprio(0);
    };

    stage(0, 0); stage(1, 1);             // 6 loads/thread in flight
    int bufc = 0;                         // compute buffer = t % 3
    for (int t = 0; t < 30; ++t) {        // steady state: tiles 0..29
        asm volatile("s_waitcnt vmcnt(3)" ::: "memory");   // my tile-t loads done
        __builtin_amdgcn_s_barrier();                      // everyone's done
        int bufs = bufc + 2; if (bufs >= 3) bufs -= 3;     // buf of tile t-1 (reads done)
        stage(t + 2, bufs);
        compute(bufc);
        bufc = bufc + 1; if (bufc >= 3) bufc -= 3;
    }
    {   // tile 30: tile 31 still in flight
        asm volatile("s_waitcnt vmcnt(3)" ::: "memory");
        __builtin_amdgcn_s_barrier();
        compute(bufc);
        bufc = bufc + 1; if (bufc >= 3) bufc -= 3;
    }
    {   // tile 31: final drain
        asm volatile("s_waitcnt vmcnt(0)" ::: "memory");
        __builtin_amdgcn_s_barrier();
        compute(bufc);
    }

    #pragma unroll
    for (int ti = 0; ti < 4; ++ti)
        #pragma unroll
        for (int tj = 0; tj < 4; ++tj) {
            int col = c0 + wn * 64 + tj * 16 + lr;
            #pragma unroll
            for (int r = 0; r < 4; ++r) {
                int row = m0 + wm * 64 + ti * 16 + lk * 4 + r;
                size_t idx = (size_t)(b * N_ + row) * C_ + col;
                out[idx] = acc[ti][tj][r] + x[idx];
            }
        }
}

// ---------------------------------------------------------------------------
extern "C" void kernel_launch(void* const* d_in, const int* in_sizes, int n_in,
                              void* d_out, int out_size, void* d_ws, size_t ws_size,
                              hipStream_t stream) {
    (void)in_sizes; (void)n_in; (void)out_size; (void)ws_size;
    const float* xf = (const float*)d_in[0];
    const float* wq = (const float*)d_in[1];
    const float* bq = (const float*)d_in[2];
    const float* wk = (const float*)d_in[3];
    const float* bk = (const float*)d_in[4];
    const float* wv = (const float*)d_in[5];
    const float* bv = (const float*)d_in[6];
    float* out = (float*)d_out;

    // workspace layout (bytes), total needed ~109 MB:
    //   q [0,4MB) | k [4MB,8MB) | vT [8MB,40MB)
    //   WT (655KB) + xb (32MB) in [40MB, 76MB)  -- dead after qkv
    //   P (64MB) aliased over WT+xb region starting 41,943,040
    char* ws = (char*)d_ws;
    unsigned short* qb  = (unsigned short*)(ws);
    unsigned short* kb  = (unsigned short*)(ws + 4194304);
    unsigned short* vTb = (unsigned short*)(ws + 8388608);
    unsigned short* WT  = (unsigned short*)(ws + 41943040);  // [640][512]
    unsigned short* xb  = (unsigned short*)(ws + 42598400);
    unsigned short* Pb  = (unsigned short*)(ws + 41943040);  // overlaps WT+xb

    prep<<<17664, 256, 0, stream>>>(xf, xb, wq, wk, wv, WT); // xcvt + wtrans fused
    qkv<<<1280, 256, 0, stream>>>(xb, WT, bq, bk, bv, qb, kb, vTb);
    scores<<<2048, 256, 0, stream>>>(qb, kb, Pb);
    pv<<<512, 512, 0, stream>>>(Pb, vTb, xf, out);
}